// Round 2
// baseline (1022.680 us; speedup 1.0000x reference)
//
#include <hip/hip_runtime.h>

#define B_  2
#define S_  2048
#define D_  1024
#define H_  16
#define DH_ 64

typedef _Float16 f16x8 __attribute__((ext_vector_type(8)));
typedef float    f32x4 __attribute__((ext_vector_type(4)));

#define MFMA16(a, b, c) __builtin_amdgcn_mfma_f32_16x16x32_f16((a), (b), (c), 0, 0, 0)

// ---------------------------------------------------------------------------
// GEMM: out[m][n] = X[m][:] @ W[:][n] + bias[n], M=4096, N=1024, K=1024
// fp32 inputs converted to fp16 during LDS staging. Result written as fp16
// into ws with [b,h,s,dh] layout (z selects which of Q/K/V).
// Tile: 64x64, BK=32, 256 threads = 4 waves, each wave does a 32x32 quadrant.
// ---------------------------------------------------------------------------
__global__ __launch_bounds__(256) void gemm_qkv(
    const float* __restrict__ q_in, const float* __restrict__ k_in, const float* __restrict__ v_in,
    const float* __restrict__ Wq,  const float* __restrict__ Wk,  const float* __restrict__ Wv,
    const float* __restrict__ bq,  const float* __restrict__ bk,  const float* __restrict__ bv,
    _Float16* __restrict__ Qh, _Float16* __restrict__ Kh, _Float16* __restrict__ Vh)
{
    const int z = blockIdx.z;
    const float* X    = (z == 0) ? q_in : (z == 1) ? k_in : v_in;
    const float* W    = (z == 0) ? Wq   : (z == 1) ? Wk   : Wv;
    const float* bias = (z == 0) ? bq   : (z == 1) ? bk   : bv;
    _Float16*    dst  = (z == 0) ? Qh   : (z == 1) ? Kh   : Vh;

    __shared__ _Float16 As[64][40];   // [m][k], row stride 80B (16B-aligned)
    __shared__ _Float16 Bs[64][40];   // [n][k] (transposed W tile)

    const int tid  = threadIdx.x;
    const int lane = tid & 63, wave = tid >> 6;
    const int quad = lane >> 4, col = lane & 15;
    const int wm = wave >> 1, wn = wave & 1;
    const int bm0 = blockIdx.y * 64, bn0 = blockIdx.x * 64;

    // staging roles
    const int ar  = tid >> 2, ac  = (tid & 3) * 8;   // A: 64 rows x 32 cols
    const int bkr = tid >> 3, bn8 = (tid & 7) * 8;   // B: 32 k-rows x 64 n-cols

    f32x4 acc[2][2] = {};

    for (int k0 = 0; k0 < D_; k0 += 32) {
        // stage A tile (fp32 -> fp16)
        const float* ap = X + (size_t)(bm0 + ar) * D_ + k0 + ac;
        float4 a0 = *(const float4*)ap;
        float4 a1 = *(const float4*)(ap + 4);
        f16x8 av = { (_Float16)a0.x, (_Float16)a0.y, (_Float16)a0.z, (_Float16)a0.w,
                     (_Float16)a1.x, (_Float16)a1.y, (_Float16)a1.z, (_Float16)a1.w };
        *(f16x8*)&As[ar][ac] = av;

        // stage B tile transposed: Bs[n][k] = W[k0+k][bn0+n]
        const float* bp = W + (size_t)(k0 + bkr) * D_ + bn0 + bn8;
        float4 b0 = *(const float4*)bp;
        float4 b1 = *(const float4*)(bp + 4);
        Bs[bn8 + 0][bkr] = (_Float16)b0.x;
        Bs[bn8 + 1][bkr] = (_Float16)b0.y;
        Bs[bn8 + 2][bkr] = (_Float16)b0.z;
        Bs[bn8 + 3][bkr] = (_Float16)b0.w;
        Bs[bn8 + 4][bkr] = (_Float16)b1.x;
        Bs[bn8 + 5][bkr] = (_Float16)b1.y;
        Bs[bn8 + 6][bkr] = (_Float16)b1.z;
        Bs[bn8 + 7][bkr] = (_Float16)b1.w;
        __syncthreads();

        f16x8 a[2], b[2];
#pragma unroll
        for (int r = 0; r < 2; ++r) a[r] = *(const f16x8*)&As[wm * 32 + r * 16 + col][quad * 8];
#pragma unroll
        for (int c = 0; c < 2; ++c) b[c] = *(const f16x8*)&Bs[wn * 32 + c * 16 + col][quad * 8];
#pragma unroll
        for (int r = 0; r < 2; ++r)
#pragma unroll
            for (int c = 0; c < 2; ++c)
                acc[r][c] = MFMA16(a[r], b[c], acc[r][c]);
        __syncthreads();
    }

    // epilogue: C row = quad*4+e, col = lane&15
#pragma unroll
    for (int r = 0; r < 2; ++r)
#pragma unroll
        for (int c = 0; c < 2; ++c) {
            const int n = bn0 + wn * 32 + c * 16 + col;
            const int h = n >> 6, dh = n & 63;
            const float bi = bias[n];
#pragma unroll
            for (int e = 0; e < 4; ++e) {
                const int m = bm0 + wm * 32 + r * 16 + quad * 4 + e;
                const int bb = m >> 11, s = m & 2047;
                dst[(((size_t)(bb * H_ + h)) * S_ + s) * DH_ + dh] =
                    (_Float16)(acc[r][c][e] + bi);
            }
        }
}

// ---------------------------------------------------------------------------
// Attention: per block = 64 q-rows of one (b,h). Two passes over 2048 keys.
// Pass1: online (m,l) via MFMA scores. Pass2: recompute, write attn fp32,
// P -> LDS -> A-frag, PV MFMA with LDS-transposed V tiles. ctx -> ws (fp16).
// Staging: 256 threads x 8 halfwords = one 32x64 fp16 tile per barrier.
// ---------------------------------------------------------------------------
__global__ __launch_bounds__(256) void attn_kernel(
    const _Float16* __restrict__ Qh, const _Float16* __restrict__ Kh,
    const _Float16* __restrict__ Vh, const float* __restrict__ mask,
    float* __restrict__ attn, _Float16* __restrict__ ctx)
{
    const int bh = blockIdx.y;
    const int b = bh >> 4, h = bh & 15;
    const int qb0 = blockIdx.x * 64;
    const int tid = threadIdx.x, lane = tid & 63, wave = tid >> 6;
    const int quad = lane >> 4, col = lane & 15;

    __shared__ _Float16 Ks[32][72];     // [k_local][dh], stride 144B
    __shared__ _Float16 Vts[64][40];    // [dh][k_local], stride 80B
    __shared__ _Float16 Ps[4][16][40];  // per-wave P tile [m][k_local]

    const int qrow0 = qb0 + wave * 16;  // this wave's 16 q rows (within b,h)

    // Q A-fragments (persist): A[m=col][k=quad*8+j], k-halves 0..31 / 32..63
    const _Float16* qp = Qh + ((size_t)bh * S_ + qrow0 + col) * DH_;
    const f16x8 aq0 = *(const f16x8*)(qp + quad * 8);
    const f16x8 aq1 = *(const f16x8*)(qp + 32 + quad * 8);

    const float LOG2E = 1.4426950408889634f;
    const float scale_l2 = 0.125f * LOG2E;   // 1/sqrt(64) * log2(e)

    float mrow[4] = { -1e30f, -1e30f, -1e30f, -1e30f };
    float lrow[4] = { 0.f, 0.f, 0.f, 0.f };

    // staging role: one 32(k) x 64(dh) tile: row krow, 8 dh at kc8
    const int krow = tid >> 3, kc8 = (tid & 7) * 8;

    // ---------------- pass 1: row max & sum (base-2 domain) ----------------
    for (int kt = 0; kt < S_; kt += 32) {
        *(f16x8*)&Ks[krow][kc8] =
            *(const f16x8*)(Kh + ((size_t)bh * S_ + kt + krow) * DH_ + kc8);
        __syncthreads();
#pragma unroll
        for (int c = 0; c < 2; ++c) {
            f16x8 b0 = *(const f16x8*)&Ks[c * 16 + col][quad * 8];
            f16x8 b1 = *(const f16x8*)&Ks[c * 16 + col][32 + quad * 8];
            f32x4 sc = {};
            sc = MFMA16(aq0, b0, sc);
            sc = MFMA16(aq1, b1, sc);
#pragma unroll
            for (int e = 0; e < 4; ++e) {
                const int q = qrow0 + quad * 4 + e;
                const float s2 = sc[e] * scale_l2 +
                    mask[((size_t)b * S_ + q) * S_ + kt + c * 16 + col] * LOG2E;
                const float nm = fmaxf(mrow[e], s2);
                lrow[e] = lrow[e] * exp2f(mrow[e] - nm) + exp2f(s2 - nm);
                mrow[e] = nm;
            }
        }
        __syncthreads();
    }

    // merge (m,l) across the 16 lanes (cols) holding each row
#pragma unroll
    for (int off = 1; off < 16; off <<= 1) {
#pragma unroll
        for (int e = 0; e < 4; ++e) {
            const float om = __shfl_xor(mrow[e], off, 64);
            const float ol = __shfl_xor(lrow[e], off, 64);
            const float nm = fmaxf(mrow[e], om);
            lrow[e] = lrow[e] * exp2f(mrow[e] - nm) + ol * exp2f(om - nm);
            mrow[e] = nm;
        }
    }
    float invl[4];
#pragma unroll
    for (int e = 0; e < 4; ++e) invl[e] = 1.0f / lrow[e];

    // ---------------- pass 2: attn write + PV ----------------
    f32x4 cacc[4] = {};
    for (int kt = 0; kt < S_; kt += 32) {
        // restage K tile (32 x 64)
        *(f16x8*)&Ks[krow][kc8] =
            *(const f16x8*)(Kh + ((size_t)bh * S_ + kt + krow) * DH_ + kc8);
        // stage V tile transposed: Vts[dh][k_local]
        {
            f16x8 v0 = *(const f16x8*)(Vh + ((size_t)bh * S_ + kt + krow) * DH_ + kc8);
#pragma unroll
            for (int j = 0; j < 8; ++j) Vts[kc8 + j][krow] = v0[j];
        }
        __syncthreads();

#pragma unroll
        for (int c = 0; c < 2; ++c) {
            f16x8 b0 = *(const f16x8*)&Ks[c * 16 + col][quad * 8];
            f16x8 b1 = *(const f16x8*)&Ks[c * 16 + col][32 + quad * 8];
            f32x4 sc = {};
            sc = MFMA16(aq0, b0, sc);
            sc = MFMA16(aq1, b1, sc);
#pragma unroll
            for (int e = 0; e < 4; ++e) {
                const int q = qrow0 + quad * 4 + e;
                const float s2 = sc[e] * scale_l2 +
                    mask[((size_t)b * S_ + q) * S_ + kt + c * 16 + col] * LOG2E;
                const float p = exp2f(s2 - mrow[e]) * invl[e];
                attn[((size_t)bh * S_ + q) * S_ + kt + c * 16 + col] = p;
                Ps[wave][quad * 4 + e][c * 16 + col] = (_Float16)p;
            }
        }

        // PV: A = P (16x32), B = V (32 x 64 as 4 n-tiles)
        {
            f16x8 apf = *(const f16x8*)&Ps[wave][col][quad * 8];
#pragma unroll
            for (int nt = 0; nt < 4; ++nt) {
                f16x8 bv = *(const f16x8*)&Vts[nt * 16 + col][quad * 8];
                cacc[nt] = MFMA16(apf, bv, cacc[nt]);
            }
        }
        __syncthreads();
    }

    // write ctx (merge heads): [b][s][h*64+dh], fp16
#pragma unroll
    for (int nt = 0; nt < 4; ++nt)
#pragma unroll
        for (int e = 0; e < 4; ++e) {
            const int s = qrow0 + quad * 4 + e;
            const int d = h * DH_ + nt * 16 + col;
            ctx[((size_t)b * S_ + s) * D_ + d] = (_Float16)cacc[nt][e];
        }
}

// ---------------------------------------------------------------------------
// Output projection: out = ctx(fp16) @ Wo + bo, fp32 result to d_out.
// ---------------------------------------------------------------------------
__global__ __launch_bounds__(256) void gemm_out(
    const _Float16* __restrict__ X, const float* __restrict__ W,
    const float* __restrict__ bias, float* __restrict__ out)
{
    __shared__ _Float16 As[64][40];
    __shared__ _Float16 Bs[64][40];

    const int tid  = threadIdx.x;
    const int lane = tid & 63, wave = tid >> 6;
    const int quad = lane >> 4, col = lane & 15;
    const int wm = wave >> 1, wn = wave & 1;
    const int bm0 = blockIdx.y * 64, bn0 = blockIdx.x * 64;

    const int ar  = tid >> 2, ac  = (tid & 3) * 8;
    const int bkr = tid >> 3, bn8 = (tid & 7) * 8;

    f32x4 acc[2][2] = {};

    for (int k0 = 0; k0 < D_; k0 += 32) {
        *(f16x8*)&As[ar][ac] = *(const f16x8*)(X + (size_t)(bm0 + ar) * D_ + k0 + ac);

        const float* bp = W + (size_t)(k0 + bkr) * D_ + bn0 + bn8;
        float4 b0 = *(const float4*)bp;
        float4 b1 = *(const float4*)(bp + 4);
        Bs[bn8 + 0][bkr] = (_Float16)b0.x;
        Bs[bn8 + 1][bkr] = (_Float16)b0.y;
        Bs[bn8 + 2][bkr] = (_Float16)b0.z;
        Bs[bn8 + 3][bkr] = (_Float16)b0.w;
        Bs[bn8 + 4][bkr] = (_Float16)b1.x;
        Bs[bn8 + 5][bkr] = (_Float16)b1.y;
        Bs[bn8 + 6][bkr] = (_Float16)b1.z;
        Bs[bn8 + 7][bkr] = (_Float16)b1.w;
        __syncthreads();

        f16x8 a[2], b[2];
#pragma unroll
        for (int r = 0; r < 2; ++r) a[r] = *(const f16x8*)&As[wm * 32 + r * 16 + col][quad * 8];
#pragma unroll
        for (int c = 0; c < 2; ++c) b[c] = *(const f16x8*)&Bs[wn * 32 + c * 16 + col][quad * 8];
#pragma unroll
        for (int r = 0; r < 2; ++r)
#pragma unroll
            for (int c = 0; c < 2; ++c)
                acc[r][c] = MFMA16(a[r], b[c], acc[r][c]);
        __syncthreads();
    }

#pragma unroll
    for (int r = 0; r < 2; ++r)
#pragma unroll
        for (int c = 0; c < 2; ++c) {
            const int n = bn0 + wn * 32 + c * 16 + col;
            const float bi = bias[n];
#pragma unroll
            for (int e = 0; e < 4; ++e) {
                const int m = bm0 + wm * 32 + r * 16 + quad * 4 + e;
                out[(size_t)m * D_ + n] = acc[r][c][e] + bi;
            }
        }
}

extern "C" void kernel_launch(void* const* d_in, const int* in_sizes, int n_in,
                              void* d_out, int out_size, void* d_ws, size_t ws_size,
                              hipStream_t stream) {
    const float* q_in = (const float*)d_in[0];
    const float* k_in = (const float*)d_in[1];
    const float* v_in = (const float*)d_in[2];
    const float* mask = (const float*)d_in[3];
    const float* Wq   = (const float*)d_in[4];
    const float* bq   = (const float*)d_in[5];
    const float* Wk   = (const float*)d_in[6];
    const float* bk   = (const float*)d_in[7];
    const float* Wv   = (const float*)d_in[8];
    const float* bv   = (const float*)d_in[9];
    const float* Wo   = (const float*)d_in[10];
    const float* bo   = (const float*)d_in[11];

    float* out  = (float*)d_out;
    float* attn = out + (size_t)B_ * S_ * D_;   // 4,194,304 floats offset

    const size_t elems = (size_t)B_ * H_ * S_ * DH_;  // 4,194,304 per tensor
    _Float16* Qh  = (_Float16*)d_ws;
    _Float16* Kh  = Qh + elems;
    _Float16* Vh  = Kh + elems;
    _Float16* Ctx = Vh + elems;

    gemm_qkv<<<dim3(16, 64, 3), 256, 0, stream>>>(q_in, k_in, v_in,
                                                  Wq, Wk, Wv, bq, bk, bv,
                                                  Qh, Kh, Vh);
    attn_kernel<<<dim3(32, 32), 256, 0, stream>>>(Qh, Kh, Vh, mask, attn, Ctx);
    gemm_out<<<dim3(16, 64), 256, 0, stream>>>(Ctx, Wo, bo, out);
}